// Round 1
// 511.146 us; speedup vs baseline: 1.0516x; 1.0516x over previous
//
#include <hip/hip_runtime.h>
#include <cstdint>
#include <cstddef>

// ---------------------------------------------------------------------------
// MultiHeadCrossAttention W8A8 fake-quant, MI355X (gfx950)
// B=2, N=4096, M=512, C=2048, H=16, Dh=128
//
// R4: the two big GEMMs (q-proj, out-proj) moved from the 128^2 2-barrier
// structure (~706 TF, MfmaUtil 30%) to the 256^2 8-wave deep-pipelined
// schedule (T3+T4 counted vmcnt + T5 setprio, guide §5.5):
//   - 256x256 tile, BK=64, 512 thr (2Mx4N waves), LDS 2x(32KB A + 32KB B)
//   - tile t+2's global_load_lds issued inside tile t's phase 3 after an
//     lgkmcnt(0)-guarded handoff barrier; steady-state wait is vmcnt(8)
//     once per K-tile (t+1's 8 loads never drained at a barrier)
//   - 4 phases/K-tile, 16 MFMA per phase inside setprio(1/0)
//   - pre-packed fragment-stream operands keep LDS linear + conflict-free
//     (measured SQ_LDS_BANK_CONFLICT = 0), so no swizzle needed
//   - grid 256 blocks = 1/CU, bijective XCD chunk swizzle (nwg%8==0)
//
// GEMM-operand pack (M x K, 128-row panels, 32-col chunk groups):
//   idx(row,col) = ((p*KT + kt)*8 + c)*512 + (quad*16 + lm)*8 + j
//   p=row>>7, c=(row>>4)&7, lm=row&15, kt=col>>5, quad=(col>>3)&3, j=col&7
//   One 512-elem chunk = one 16x32 mfma_16x16x32 fragment-set; lane l owns
//   elems [l*8, l*8+8) both in HBM and in LDS (gld16 identity mapping).
// ---------------------------------------------------------------------------

typedef __bf16 bf16_t;
typedef __bf16 bf16x8 __attribute__((ext_vector_type(8)));
typedef float f32x4 __attribute__((ext_vector_type(4)));

__device__ __forceinline__ void gld16(void* lds, const void* g) {
    __builtin_amdgcn_global_load_lds(
        (__attribute__((address_space(1))) uint32_t*)(uintptr_t)g,
        (__attribute__((address_space(3))) uint32_t*)(uint32_t)(uintptr_t)lds,
        16, 0, 0);
}

__device__ __forceinline__ void load8(const float* p, int i, float* v) {
    const float4* p4 = (const float4*)p;
    float4 a = p4[2 * i], b = p4[2 * i + 1];
    v[0] = a.x; v[1] = a.y; v[2] = a.z; v[3] = a.w;
    v[4] = b.x; v[5] = b.y; v[6] = b.z; v[7] = b.w;
}
__device__ __forceinline__ void load8(const bf16_t* p, int i, float* v) {
    bf16x8 t = ((const bf16x8*)p)[i];
#pragma unroll
    for (int j = 0; j < 8; ++j) v[j] = (float)t[j];
}

// ---------------------------------------------------------------------------
// Per-row fake-quant (QUANT=1) or plain convert (QUANT=0), output packed.
// ---------------------------------------------------------------------------
template <int QUANT, typename T>
__global__ __launch_bounds__(256) void rowpack(const T* __restrict__ in,
                                               bf16_t* __restrict__ out, int K) {
    const int tid = threadIdx.x;
    const size_t row = blockIdx.x;
    const T* rp = in + row * (size_t)K;
    const int n8 = K >> 3;
    float scale = 1.0f;
    if (QUANT) {
        float m = 0.f;
        for (int i = tid; i < n8; i += 256) {
            float v[8];
            load8(rp, i, v);
#pragma unroll
            for (int j = 0; j < 8; ++j) m = fmaxf(m, fabsf(v[j]));
        }
        __shared__ float red[256];
        red[tid] = m;
        __syncthreads();
        for (int s = 128; s > 0; s >>= 1) {
            if (tid < s) red[tid] = fmaxf(red[tid], red[tid + s]);
            __syncthreads();
        }
        scale = fmaxf(red[0] * (1.0f / 127.0f), 1e-8f);
    }
    const int KT = K >> 5;
    const int p = (int)(row >> 7), c = ((int)row >> 4) & 7, lm = (int)row & 15;
    for (int i = tid; i < n8; i += 256) {
        const int col = i << 3;
        const int kt = col >> 5, quad = (col >> 3) & 3;
        float v[8];
        load8(rp, i, v);
        bf16x8 o8;
#pragma unroll
        for (int j = 0; j < 8; ++j) {
            float q = v[j];
            if (QUANT) {
                q = rintf(q / scale);  // RNE, matches jnp.round
                q = fminf(127.f, fmaxf(-127.f, q)) * scale;
            }
            o8[j] = (bf16_t)q;
        }
        const size_t dst = ((size_t)(p * KT + kt) * 8 + c) * 512 + (quad * 16 + lm) * 8;
        *(bf16x8*)(out + dst) = o8;
    }
}

// ---------------------------------------------------------------------------
// Epilogue stores (shared by the GEMM kernels).
// MODE 0: attention-packed q.  MODE 1: natural fp32.  MODE 2: kv split pack.
// ---------------------------------------------------------------------------
template <int MODE>
__device__ __forceinline__ void epi_store(void* C, int N, int row, int col, float v) {
    if (MODE == 1) {
        ((float*)C)[(size_t)row * N + col] = v;
    } else if (MODE == 0) {
        const int b = row >> 12, n = row & 4095;
        const int h = col >> 7, d = col & 127;
        const int p = n >> 6, mt = (n >> 4) & 3, lmq = n & 15;
        const int kq = d >> 5, qq = (d >> 3) & 3, jq = d & 7;
        const size_t idx = (((size_t)(b * 16 + h) * 64 + p) * 16 + kq * 4 + mt) * 512 +
                           (qq * 16 + lmq) * 8 + jq;
        ((bf16_t*)C)[idx] = (bf16_t)v;
    } else {
        const int b = row >> 9, m = row & 511;
        const int half = col >> 11, h = (col >> 7) & 15, d = col & 127;
        const int t8 = m >> 6;
        bf16_t* out = (bf16_t*)C;
        if (half == 0) {
            const int nt = (m >> 4) & 3, lmk = m & 15;
            const int kc = d >> 5, qk = (d >> 3) & 3, jk = d & 7;
            const size_t idx = (((size_t)(b * 16 + h) * 8 + t8) * 16 + kc * 4 + nt) * 512 +
                               (qk * 16 + lmk) * 8 + jk;
            out[idx] = (bf16_t)v;
        } else {
            const int kv2 = (m >> 5) & 1, qv = (m >> 3) & 3, jv = m & 7;
            const int ntv = d >> 4, lmv = d & 15;
            const size_t idx = 2097152 +
                (((size_t)(b * 16 + h) * 8 + t8) * 16 + kv2 * 8 + ntv) * 512 +
                (qv * 16 + lmv) * 8 + jv;
            out[idx] = (bf16_t)v;
        }
    }
}

// ---------------------------------------------------------------------------
// Stage one 256x64 K-tile pair (A and B) into LDS: 32 chunks each, 8 waves
// x 4 chunks, 8 gld16/thread.  Chunk ci = (h*2 + kt2)*8 + c  (h = 128-row
// half, kt2 = 32-col half of BK, c = 16-row group).
// ---------------------------------------------------------------------------
__device__ __forceinline__ void stage_tile256(const bf16_t* __restrict__ A,
                                              const bf16_t* __restrict__ B,
                                              bf16_t* sa, bf16_t* sb,
                                              int pa, int pb, int KT, int t,
                                              int w, int l) {
#pragma unroll
    for (int it = 0; it < 4; ++it) {
        const int ci = w * 4 + it;                      // 0..31, wave-uniform
        const int h = ci >> 4, kt2 = (ci >> 3) & 1, c = ci & 7;
        const size_t ga = (((size_t)(pa + h) * KT + (2 * t + kt2)) * 8 + c) * 512 + l * 8;
        const size_t gb = (((size_t)(pb + h) * KT + (2 * t + kt2)) * 8 + c) * 512 + l * 8;
        gld16(sa + ci * 512, A + ga);
        gld16(sb + ci * 512, B + gb);
    }
}

// ---------------------------------------------------------------------------
// 256x256 deep-pipelined GEMM on packed operands: C = A B^T + bias.
// 512 threads = 8 waves (2M x 4N); per-wave output 128x64 (acc[8][4]).
// Schedule per K-tile t (buffers cur = t&1):
//   ph0: ds_read B[4][2] + A rows 0-1 | bar | lgkm0 | prio1 16xMFMA prio0 | bar
//   ph1: ds_read A rows 2-3          | bar | lgkm0 | prio1 16xMFMA prio0 | bar
//   ph2: ds_read A rows 4-5          | bar | lgkm0 | prio1 16xMFMA prio0 | bar
//   ph3: ds_read A rows 6-7, lgkm0, bar(handoff: all reads of buf[cur] done),
//        issue tile t+2 -> buf[cur], prio1 16xMFMA prio0,
//        vmcnt(8) (t+1 landed, t+2 still in flight), bar(publish t+1)
// Loads are NEVER drained to vmcnt(0) in steady state.
// ---------------------------------------------------------------------------
template <int MODE>
__global__ __launch_bounds__(512, 1) void gemm_pk8(const bf16_t* __restrict__ A,
                                                   const bf16_t* __restrict__ B,
                                                   const float* __restrict__ bias,
                                                   void* __restrict__ C,
                                                   int N, int K) {
    __shared__ __align__(16) bf16_t sA[2][16384];  // 2 x 32KB
    __shared__ __align__(16) bf16_t sB[2][16384];  // total 128KB -> 1 block/CU

    const int tid = threadIdx.x;
    const int l = tid & 63, w = tid >> 6;
    const int lm = l & 15, quad = l >> 4;
    const int wm = w & 1, wn = w >> 1;  // 2 x 4 wave grid

    // bijective XCD chunk swizzle (nwg = 256, %8 == 0): XCD x gets 32
    // consecutive s-values -> contiguous A-panel rows per XCD L2.
    const int nwg = gridDim.x;
    const int bid = blockIdx.x;
    const int s = (bid & 7) * (nwg >> 3) + (bid >> 3);
    const int bx = s & 7, by = s >> 3;  // GX = N/256 = 8

    const int KT = K >> 5;
    const int NT = K >> 6;  // K-tiles of 64
    const int pa = by * 2, pb = bx * 2;

    // ---- prologue: tiles 0 and 1 in flight; publish tile 0 only ----
    stage_tile256(A, B, sA[0], sB[0], pa, pb, KT, 0, w, l);
    __builtin_amdgcn_sched_barrier(0);  // keep issue order: tile0 loads oldest
    stage_tile256(A, B, sA[1], sB[1], pa, pb, KT, 1, w, l);
    asm volatile("s_waitcnt vmcnt(8)" ::: "memory");  // tile0's 8 landed
    __builtin_amdgcn_s_barrier();

    f32x4 acc[8][4] = {};

    for (int t = 0; t < NT; ++t) {
        const bf16_t* sa = sA[t & 1];
        const bf16_t* sb = sB[t & 1];
        bf16x8 bfr[4][2];
        bf16x8 af[2][2];

        // ---------------- phase 0: B full tile + A rows 0-1 ----------------
#pragma unroll
        for (int j = 0; j < 4; ++j)
#pragma unroll
            for (int k2 = 0; k2 < 2; ++k2)
                bfr[j][k2] = *(const bf16x8*)(
                    sb + ((((wn >> 1) * 2 + k2) * 8 + (wn & 1) * 4 + j) * 512) + l * 8);
#pragma unroll
        for (int ii = 0; ii < 2; ++ii)
#pragma unroll
            for (int k2 = 0; k2 < 2; ++k2)
                af[ii][k2] = *(const bf16x8*)(sa + (((wm * 2 + k2) * 8 + ii) * 512) + l * 8);
        __builtin_amdgcn_s_barrier();
        asm volatile("s_waitcnt lgkmcnt(0)" ::: "memory");
        __builtin_amdgcn_sched_barrier(0);
        __builtin_amdgcn_s_setprio(1);
#pragma unroll
        for (int ii = 0; ii < 2; ++ii)
#pragma unroll
            for (int j = 0; j < 4; ++j)
#pragma unroll
                for (int k2 = 0; k2 < 2; ++k2)
                    acc[ii][j] = __builtin_amdgcn_mfma_f32_16x16x32_bf16(
                        af[ii][k2], bfr[j][k2], acc[ii][j], 0, 0, 0);
        __builtin_amdgcn_s_setprio(0);
        __builtin_amdgcn_s_barrier();

        // ---------------- phases 1,2: A rows 2-3 / 4-5 ----------------
#pragma unroll
        for (int q = 1; q <= 2; ++q) {
#pragma unroll
            for (int ii = 0; ii < 2; ++ii)
#pragma unroll
                for (int k2 = 0; k2 < 2; ++k2)
                    af[ii][k2] = *(const bf16x8*)(
                        sa + (((wm * 2 + k2) * 8 + (q * 2 + ii)) * 512) + l * 8);
            __builtin_amdgcn_s_barrier();
            asm volatile("s_waitcnt lgkmcnt(0)" ::: "memory");
            __builtin_amdgcn_sched_barrier(0);
            __builtin_amdgcn_s_setprio(1);
#pragma unroll
            for (int ii = 0; ii < 2; ++ii)
#pragma unroll
                for (int j = 0; j < 4; ++j)
#pragma unroll
                    for (int k2 = 0; k2 < 2; ++k2)
                        acc[q * 2 + ii][j] = __builtin_amdgcn_mfma_f32_16x16x32_bf16(
                            af[ii][k2], bfr[j][k2], acc[q * 2 + ii][j], 0, 0, 0);
            __builtin_amdgcn_s_setprio(0);
            __builtin_amdgcn_s_barrier();
        }

        // ---------------- phase 3: A rows 6-7 + handoff + prefetch ----------------
#pragma unroll
        for (int ii = 0; ii < 2; ++ii)
#pragma unroll
            for (int k2 = 0; k2 < 2; ++k2)
                af[ii][k2] = *(const bf16x8*)(
                    sa + (((wm * 2 + k2) * 8 + (6 + ii)) * 512) + l * 8);
        asm volatile("s_waitcnt lgkmcnt(0)" ::: "memory");  // my reads of buf[cur] done
        __builtin_amdgcn_s_barrier();  // ALL waves done reading buf[cur]
        if (t + 2 < NT)                // overwrite buf[cur] with tile t+2
            stage_tile256(A, B, sA[t & 1], sB[t & 1], pa, pb, KT, t + 2, w, l);
        __builtin_amdgcn_sched_barrier(0);  // issue loads before MFMA cluster
        __builtin_amdgcn_s_setprio(1);
#pragma unroll
        for (int ii = 0; ii < 2; ++ii)
#pragma unroll
            for (int j = 0; j < 4; ++j)
#pragma unroll
                for (int k2 = 0; k2 < 2; ++k2)
                    acc[6 + ii][j] = __builtin_amdgcn_mfma_f32_16x16x32_bf16(
                        af[ii][k2], bfr[j][k2], acc[6 + ii][j], 0, 0, 0);
        __builtin_amdgcn_s_setprio(0);
        if (t + 2 < NT)  // t+1's 8 loads landed; t+2's 8 stay in flight
            asm volatile("s_waitcnt vmcnt(8)" ::: "memory");
        else             // tail: drain remaining prefetch (t+1) fully
            asm volatile("s_waitcnt vmcnt(0)" ::: "memory");
        __builtin_amdgcn_s_barrier();  // publish tile t+1
    }

    // ---- epilogue ----
#pragma unroll
    for (int i = 0; i < 8; ++i) {
#pragma unroll
        for (int j = 0; j < 4; ++j) {
            const int col = bx * 256 + wn * 64 + j * 16 + lm;
            const float bv = bias[col];
#pragma unroll
            for (int r = 0; r < 4; ++r) {
                const int row = by * 256 + wm * 128 + i * 16 + quad * 4 + r;
                epi_store<MODE>(C, N, row, col, acc[i][j][r] + bv);
            }
        }
    }
}

// ---------------------------------------------------------------------------
// kv GEMM: 64x128 tile, BK=64, 4 waves (2x2: wave = 32 rows x 64 cols).
// 512 blocks -> 2 blocks/CU.  Epilogue: MODE2 kv split pack.
// ---------------------------------------------------------------------------
__global__ __launch_bounds__(256) void gemm_kv(const bf16_t* __restrict__ A,
                                               const bf16_t* __restrict__ B,
                                               const float* __restrict__ bias,
                                               bf16_t* __restrict__ C,
                                               int N, int K) {
    __shared__ __align__(16) bf16_t sA[4096];  // 8 chunks (64 rows x 64 k)
    __shared__ __align__(16) bf16_t sB[8192];  // 16 chunks

    const int tid = threadIdx.x;
    const int l = tid & 63, w = tid >> 6;
    const int lm = l & 15, quad = l >> 4;
    const int wm = w & 1, wn = w >> 1;
    const int KT = K >> 5;
    const int p = blockIdx.y >> 1, hh = blockIdx.y & 1;  // 64-row half of 128-panel
    const size_t aPan = (size_t)p * KT * 8 * 512;
    const size_t bBase = (size_t)blockIdx.x * KT * 8 * 512;

    f32x4 acc[2][4] = {};
    const int NIT = K >> 6;
    for (int kt = 0; kt < NIT; ++kt) {
        __syncthreads();
#pragma unroll
        for (int it = 0; it < 2; ++it) {
            const int lc = it * 4 + w;  // 0..7
            const int s = lc >> 2, cc = lc & 3;
            gld16(sA + lc * 512,
                  A + aPan + ((size_t)(kt * 2 + s) * 8 + hh * 4 + cc) * 512 + l * 8);
        }
#pragma unroll
        for (int it = 0; it < 4; ++it) {
            const int lc = it * 4 + w;  // 0..15
            gld16(sB + lc * 512, B + bBase + ((size_t)kt * 16 + lc) * 512 + l * 8);
        }
        __syncthreads();
#pragma unroll
        for (int s = 0; s < 2; ++s) {
            bf16x8 af[2], bfr[4];
#pragma unroll
            for (int i = 0; i < 2; ++i)
                af[i] = *(const bf16x8*)(sA + (s * 4 + wm * 2 + i) * 512 + l * 8);
#pragma unroll
            for (int j = 0; j < 4; ++j)
                bfr[j] = *(const bf16x8*)(sB + (s * 8 + wn * 4 + j) * 512 + l * 8);
#pragma unroll
            for (int i = 0; i < 2; ++i)
#pragma unroll
                for (int j = 0; j < 4; ++j)
                    acc[i][j] =
                        __builtin_amdgcn_mfma_f32_16x16x32_bf16(af[i], bfr[j], acc[i][j], 0, 0, 0);
        }
    }
#pragma unroll
    for (int i = 0; i < 2; ++i) {
#pragma unroll
        for (int j = 0; j < 4; ++j) {
            const int col = blockIdx.x * 128 + wn * 64 + j * 16 + lm;
            const float bv = bias[col];
#pragma unroll
            for (int r = 0; r < 4; ++r) {
                const int row = blockIdx.y * 64 + wm * 32 + i * 16 + quad * 4 + r;
                epi_store<2>(C, N, row, col, acc[i][j][r] + bv);
            }
        }
    }
}

// ---------------------------------------------------------------------------
// Fused attention, 64 q-rows per block, 128-key staging groups.
// S register-resident (128 VGPR), sP aliases sQ (Q dead after S-phase).
// LDS: 16 + 32 + 2 = 50KB -> 3 blocks/CU ceiling.
// ---------------------------------------------------------------------------
__global__ __launch_bounds__(256, 2) void attn64(const bf16_t* __restrict__ qpk,
                                                 const bf16_t* __restrict__ kvpk,
                                                 bf16_t* __restrict__ o) {
    constexpr float SCALE = 0.08838834764831845f;  // 1/sqrt(128)
    __shared__ __align__(16) bf16_t sQP[8192];   // 16KB: Q chunks kc*4+mt, then P chunks mt*4+kv
    __shared__ __align__(16) bf16_t sKV[16384];  // 32KB: 32 chunks per 128-key group
    __shared__ float redM[4][64];
    __shared__ float redS[4][64];

    const int tid = threadIdx.x;
    const int l = tid & 63, w = tid >> 6;
    const int lm = l & 15, quad = l >> 4;
    const int b = blockIdx.z, h = blockIdx.y;
    const int p = blockIdx.x;  // 64-row q panel
    const int bh = b * 16 + h;
    const size_t qbase = ((size_t)bh * 64 + p) * 8192;
    const size_t kbase = (size_t)bh * 65536;
    const size_t vbase = 2097152 + (size_t)bh * 65536;

    // ---- stage Q [64 x 128] ----
#pragma unroll
    for (int it = 0; it < 4; ++it) {
        const int c = it * 4 + w;
        gld16(sQP + c * 512, qpk + qbase + (size_t)c * 512 + l * 8);
    }

    // ---- S = Q K^T over 4 key-groups of 128 ----
    f32x4 sfr[8][4] = {};
#pragma unroll
    for (int g = 0; g < 4; ++g) {
        __syncthreads();
#pragma unroll
        for (int it = 0; it < 8; ++it) {
            const int c = it * 4 + w;  // 0..31
            gld16(sKV + c * 512, kvpk + kbase + ((size_t)g * 32 + c) * 512 + l * 8);
        }
        __syncthreads();
#pragma unroll
        for (int kc = 0; kc < 4; ++kc) {
#pragma unroll
            for (int kk = 0; kk < 2; ++kk) {
                bf16x8 bb = *(const bf16x8*)(sKV + (kk * 16 + kc * 4 + w) * 512 + l * 8);
#pragma unroll
                for (int mt = 0; mt < 4; ++mt) {
                    bf16x8 aa = *(const bf16x8*)(sQP + (kc * 4 + mt) * 512 + l * 8);
                    sfr[g * 2 + kk][mt] =
                        __builtin_amdgcn_mfma_f32_16x16x32_bf16(aa, bb, sfr[g * 2 + kk][mt], 0, 0, 0);
                }
            }
        }
    }

    // ---- softmax: lane holds rows mt*16+quad*4+r, cols t8*64 + w*16 + lm ----
    float inv[4][4];
    {
        float mymax[4][4];
#pragma unroll
        for (int mt = 0; mt < 4; ++mt)
#pragma unroll
            for (int r = 0; r < 4; ++r) {
                float m = -3.0e38f;
#pragma unroll
                for (int t8 = 0; t8 < 8; ++t8) m = fmaxf(m, sfr[t8][mt][r]);
                m = fmaxf(m, __shfl_xor(m, 1));
                m = fmaxf(m, __shfl_xor(m, 2));
                m = fmaxf(m, __shfl_xor(m, 4));
                m = fmaxf(m, __shfl_xor(m, 8));
                mymax[mt][r] = m;
            }
        if (lm == 0) {
#pragma unroll
            for (int mt = 0; mt < 4; ++mt)
#pragma unroll
                for (int r = 0; r < 4; ++r)
                    redM[w][mt * 16 + quad * 4 + r] = mymax[mt][r];
        }
        __syncthreads();
#pragma unroll
        for (int mt = 0; mt < 4; ++mt)
#pragma unroll
            for (int r = 0; r < 4; ++r) {
                const int row = mt * 16 + quad * 4 + r;
                const float M =
                    fmaxf(fmaxf(redM[0][row], redM[1][row]), fmaxf(redM[2][row], redM[3][row])) *
                    SCALE;
                float s = 0.f;
#pragma unroll
                for (int t8 = 0; t8 < 8; ++t8) {
                    const float pe = __expf(sfr[t8][mt][r] * SCALE - M);
                    sfr[t8][mt][r] = pe;
                    s += pe;
                }
                s += __shfl_xor(s, 1);
                s += __shfl_xor(s, 2);
                s += __shfl_xor(s, 4);
                s += __shfl_xor(s, 8);
                if (lm == 0) redS[w][row] = s;
            }
        __syncthreads();
#pragma unroll
        for (int mt = 0; mt < 4; ++mt)
#pragma unroll
            for (int r = 0; r < 4; ++r) {
                const int row = mt * 16 + quad * 4 + r;
                inv[mt][r] = 1.f / (redS[0][row] + redS[1][row] + redS[2][row] + redS[3][row]);
            }
    }

    // ---- O = P V over 4 key-groups of 128 ----
    f32x4 oc[4][2] = {};
    const int ktd = w >> 1;
    const int quadd = (w & 1) * 2 + (lm >> 3);
    const int jd = lm & 7;
#pragma unroll
    for (int g = 0; g < 4; ++g) {
        __syncthreads();  // prev iter's sQP/sKV reads done; S-phase reads done (g=0)
#pragma unroll
        for (int kk = 0; kk < 2; ++kk)
#pragma unroll
            for (int mt = 0; mt < 4; ++mt)
#pragma unroll
                for (int r = 0; r < 4; ++r)
                    sQP[(mt * 4 + kk * 2 + ktd) * 512 + (quadd * 16 + quad * 4 + r) * 8 + jd] =
                        (bf16_t)sfr[g * 2 + kk][mt][r];
#pragma unroll
        for (int it = 0; it < 8; ++it) {
            const int c = it * 4 + w;  // 0..31
            gld16(sKV + c * 512, kvpk + vbase + ((size_t)g * 32 + c) * 512 + l * 8);
        }
        __syncthreads();  // drains vmcnt(0); sQP(P) visible
#pragma unroll
        for (int kvf = 0; kvf < 4; ++kvf) {
            const int kk = kvf >> 1, kv2 = kvf & 1;
            bf16x8 aa[4];
#pragma unroll
            for (int mt = 0; mt < 4; ++mt)
                aa[mt] = *(const bf16x8*)(sQP + (mt * 4 + kvf) * 512 + l * 8);
#pragma unroll
            for (int ni = 0; ni < 2; ++ni) {
                bf16x8 bb =
                    *(const bf16x8*)(sKV + (kk * 16 + kv2 * 8 + w * 2 + ni) * 512 + l * 8);
#pragma unroll
                for (int mt = 0; mt < 4; ++mt)
                    oc[mt][ni] =
                        __builtin_amdgcn_mfma_f32_16x16x32_bf16(aa[mt], bb, oc[mt][ni], 0, 0, 0);
            }
        }
    }

    // ---- epilogue: normalize, write natural-layout o ----
#pragma unroll
    for (int mt = 0; mt < 4; ++mt)
#pragma unroll
        for (int ni = 0; ni < 2; ++ni)
#pragma unroll
            for (int r = 0; r < 4; ++r) {
                const int row = mt * 16 + quad * 4 + r;
                const int d = w * 32 + ni * 16 + lm;
                o[((size_t)b * 4096 + p * 64 + row) * 2048 + h * 128 + d] =
                    (bf16_t)(oc[mt][ni][r] * inv[mt][r]);
            }
}

// ---------------------------------------------------------------------------
extern "C" void kernel_launch(void* const* d_in, const int* in_sizes, int n_in,
                              void* d_out, int out_size, void* d_ws, size_t ws_size,
                              hipStream_t stream) {
    (void)in_sizes; (void)n_in; (void)out_size; (void)ws_size;
    const float* x    = (const float*)d_in[0];
    const float* cond = (const float*)d_in[1];
    const float* wq   = (const float*)d_in[2];
    const float* bq   = (const float*)d_in[3];
    const float* wkv  = (const float*)d_in[4];
    const float* bkv  = (const float*)d_in[5];
    const float* wp   = (const float*)d_in[6];
    const float* bp   = (const float*)d_in[7];

    const size_t MB = 1ull << 20;
    uint8_t* ws = (uint8_t*)d_ws;
    bf16_t* qxpk   = (bf16_t*)(ws + 0);        // 32MB qdq(x) packed; reused as o natural
    bf16_t* qpk    = (bf16_t*)(ws + 32 * MB);  // 32MB q packed; reused as qdq(o) packed
    bf16_t* wqpk   = (bf16_t*)(ws + 64 * MB);  // 8MB
    bf16_t* wkvpk  = (bf16_t*)(ws + 72 * MB);  // 16MB
    bf16_t* wppk   = (bf16_t*)(ws + 88 * MB);  // 8MB
    bf16_t* condpk = (bf16_t*)(ws + 96 * MB);  // 4MB
    bf16_t* kvpk   = (bf16_t*)(ws + 100 * MB); // 8MB (K 4MB | V 4MB)
    bf16_t* o_nat  = qxpk;
    bf16_t* opk    = qpk;

    dim3 blk(256);
    rowpack<1, float><<<8192, blk, 0, stream>>>(x, qxpk, 2048);
    rowpack<1, float><<<2048, blk, 0, stream>>>(wq, wqpk, 2048);
    rowpack<1, float><<<2048, blk, 0, stream>>>(wp, wppk, 2048);
    rowpack<0, float><<<1024, blk, 0, stream>>>(cond, condpk, 2048);
    rowpack<0, float><<<4096, blk, 0, stream>>>(wkv, wkvpk, 2048);
    // q = qdq(x) qdq(wq)^T + bq  -> attention-packed (256^2 8-wave pipeline)
    gemm_pk8<0><<<dim3(256), dim3(512), 0, stream>>>(qxpk, wqpk, bq, qpk, 2048, 2048);
    // kv = cond wkv^T + bkv      -> packed K | packed V  (64-row tiles, 512 blocks)
    gemm_kv<<<dim3(32, 16), blk, 0, stream>>>(condpk, wkvpk, bkv, kvpk, 4096, 2048);
    // attention -> o natural
    attn64<<<dim3(64, 16, 2), blk, 0, stream>>>(qpk, kvpk, o_nat);
    // qdq(o) packed
    rowpack<1, bf16_t><<<8192, blk, 0, stream>>>(o_nat, opk, 2048);
    // out = qdq(o) qdq(wp)^T + bp -> natural fp32 (256^2 8-wave pipeline)
    gemm_pk8<1><<<dim3(256), dim3(512), 0, stream>>>(opk, wppk, bp, (float*)d_out, 2048, 2048);
}